// Round 3
// baseline (224.872 us; speedup 1.0000x reference)
//
#include <hip/hip_runtime.h>
#include <math.h>

// CRITICAL: ban FMA contraction file-wide. 1-ulp iou shifts flip near-tie
// argmaxes vs numpy's correctly-rounded ref (rounds 2-4, absmax 69).
#pragma clang fp contract(off)

// Shapes: B=64, N=100, A=8732.
// Out layout (f32 flat): [0,BA) labels | [BA,5BA) boxes | [5BA,6BA) mask
//
// ROUND 3: kill the round-quantization in the iou pass. Old shape: 2240
// blocks = 8960 wave-tasks vs 8192 resident-wave capacity -> 2 scheduling
// rounds, ~55% efficiency (OccupancyPercent 45%). New shape: 2048 blocks
// (8192 waves, exact fit, launch_bounds(256,8)); each wave = 16 anchors x
// 4 gt-chunks of 25 (quarter-size tasks), 34,944 tasks statically balanced
// -> span 1.25T vs 2.0T. Row state combined intra-wave via shfl_xor; gt
// tables read from global (L1-hot, 2.4KB/b) - no LDS, no __syncthreads.
//
// colmax u64[B*N]: init by prior (prior_bits<<32 | 0: low=0 loses ties to
// genuine submissions low>=1), atomicMax'd by iou, consumed by encode
// (fused, colmax in ws) or scatter (fallback, colmax in out's boxes region).
// asq f32x2[B*N] {area_g, scurf}: in out's boxes region (encode runs last);
// scurf is globally warmed by iou submissions (stale reads = lower bound =
// safe; raised reads = valid deflated bound = safe).

#define AA 8732
#define NN 100
#define BB 64
#define CH 25                 // gts per chunk (100/4 exact)
#define AW 16                 // anchors per wave
#define TILES_PB 546          // ceil(8732/16)
#define NTASK (BB * TILES_PB) // 34944
#define NSLOT 8192            // 2048 blocks * 4 waves (exact-fit capacity)
#define NTILE 35              // ceil(AA/256) for encode grid
#define EPS_F 1e-6f
#define OVR_FLAG 0x10000
#define POS_BIT  0x8000
// qa = inter*v_rcp(uni): rel err <= ~1.8e-7. DEFL=1-5e-7 deflation makes all
// filters rigorous one-sided bounds (HW-validated rounds 8/10/11; the global
// scurf warm-up preserves the same proof: any stored value is a deflated
// lower bound of the final column max).
#define DEFL 0.9999995f
#define RT_SEED 1e-38f        // > 0: (qa >= rt) implies qa > 0, saves a cmp

__constant__ int FM_SIZE[6] = {38, 19, 10, 5, 3, 1};
__constant__ int FM_NF[6]   = {4, 6, 6, 6, 4, 4};
__constant__ int FM_OFF[6]  = {0, 5776, 7942, 8542, 8692, 8728};

__device__ __forceinline__ void geom(const float4 axy, const float4 g,
                                     float area_a, float ag,
                                     float& inter, float& uni) {
    float ltx = fmaxf(axy.x, g.x);
    float lty = fmaxf(axy.y, g.y);
    float rbx = fminf(axy.z, g.z);
    float rby = fminf(axy.w, g.w);
    float w = fmaxf(rbx - ltx, 0.0f);
    float h = fmaxf(rby - lty, 0.0f);
    inter = w * h;
    uni = area_a + ag - inter;       // uni >= max area > 0 always
}

// ---------------------------------------------------------------------------
// Prior: per (b,n), rcp-approx max IoU over the <=30 center-cell anchors,
// deflated => SAFE lower bound of the column max. Writes colmax init AND the
// asq table {area_g, scurf_seed}.
// ---------------------------------------------------------------------------
__global__ void prior_kernel(const float4* __restrict__ gt_boxes,
                             const float4* __restrict__ anchors_xyxy,
                             unsigned long long* __restrict__ colmax,
                             float2* __restrict__ asq) {
    const int b = blockIdx.x;
    const int n = threadIdx.x;
    if (n >= NN) return;
    float4 g = gt_boxes[b * NN + n];
    float ag = (g.z - g.x) * (g.w - g.y);
    float cx = (g.x + g.z) * 0.5f;
    float cy = (g.y + g.w) * 0.5f;
    float best = 0.0f;
    for (int f = 0; f < 6; f++) {
        int s = FM_SIZE[f];
        int j = (int)(cx * (float)s); j = j < s - 1 ? j : s - 1;
        int i = (int)(cy * (float)s); i = i < s - 1 ? i : s - 1;
        int base = FM_OFF[f] + (i * s + j) * FM_NF[f];
        for (int k = 0; k < FM_NF[f]; k++) {
            float4 an = anchors_xyxy[base + k];
            float area_a = (an.z - an.x) * (an.w - an.y);
            float inter, uni;
            geom(an, g, area_a, ag, inter, uni);
            best = fmaxf(best, inter * __builtin_amdgcn_rcpf(uni));
        }
    }
    float defl = best * DEFL;        // <= colM*(1-3.2e-7): safe lower bound
    colmax[b * NN + n] = ((unsigned long long)__float_as_uint(defl)) << 32;
    asq[b * NN + n] = make_float2(ag, defl);
}

// ---------------------------------------------------------------------------
// Exact-fit iou pass. 2048 blocks x 256. Wave task = (b, 16-anchor tile):
// lane = (anchor al = lane&15) x (gt-chunk c = lane>>4, gts [25c,25c+25)).
// Static contiguous task ranges balance 34,944 tasks over 8192 wave-slots
// (4 or 5 tasks/slot -> span 5 quarter-tasks = 1.25T).
// Row: per-lane record mask vs running deflated rt; rt combined across the
// 4 chunks (shfl_xor 16,32); per-chunk replay vs final rt; cross-chunk
// argmax via packed (iou_bits<<32)|(NN-bi) max (bigger low = smaller n =
// numpy first-max; chunks without candidates contribute (0|100) == the
// numpy all-zero default bv=0,bi=0).
// Col: __any trigger vs global scurf (rare after prior priming); 16-lane
// group butterfly (xor 8,4,2,1), group-lane-0 submits atomicMax + global
// scurf warm-up. Padded lanes (a>=AA) clamp to anchor AA-1: genuine clone
// values, idempotent under max; their slot write is skipped.
// ---------------------------------------------------------------------------
__global__ __launch_bounds__(256, 8) void iou_row_kernel(
        const float4* __restrict__ gt_boxes,        // B*N xyxy
        const float4* __restrict__ anchors_xyxy,    // A
        float2* __restrict__ asq,                   // B*N {area, scurf}
        unsigned long long* __restrict__ colmax,    // B*N packed, prior-init
        int* __restrict__ out_slot)                 // -> out[5BA..6BA)
{
    const int tid  = threadIdx.x;
    const int lane = tid & 63;
    const int slot = blockIdx.x * 4 + (tid >> 6);
    const int t0 = (slot * NTASK) >> 13;            // * 34944 / 8192
    const int t1 = ((slot + 1) * NTASK) >> 13;
    const int al = lane & 15;                       // anchor within tile
    const int c  = lane >> 4;                       // gt chunk 0..3
    const int n0 = c * CH;

    for (int t = t0; t < t1; t++) {
        const int b    = t / TILES_PB;              // const-div -> mul magic
        const int tile = t - b * TILES_PB;
        const int a = tile * AW + al;
        const bool valid = (a < AA);
        const int ac = valid ? a : (AA - 1);
        const float4 axy = anchors_xyxy[ac];
        const float area_a = (axy.z - axy.x) * (axy.w - axy.y);
        const unsigned lowkey = (unsigned)(AA - ac); // bigger = lower anchor
        const float4* __restrict__ gb = gt_boxes + b * NN;
        float2* __restrict__ aq = asq + b * NN;
        unsigned long long* __restrict__ cm = colmax + b * NN;

        // ---------------- Phase A: 25-gt chunk ----------------
        float rt = RT_SEED;        // (qa >= rt) implies qa > 0
        unsigned rm = 0;
        #pragma unroll 5
        for (int i = 0; i < CH; i++) {
            const int n = n0 + i;
            float4 g = gb[n];
            float2 aw = aq[n];     // .y stale-read = lower bound, safe
            float inter, uni;
            geom(axy, g, area_a, aw.x, inter, uni);
            float qa = inter * __builtin_amdgcn_rcpf(uni);
            bool r = (qa >= rt);                     // row near-record
            rt = fmaxf(rt, qa * DEFL);
            rm |= (r ? 1u : 0u) << i;
            if (__any((int)(qa >= aw.y))) {          // column trigger (rare)
                float iou = inter / uni;             // exact IEEE == numpy
                bool cc = (qa >= aw.y);
                unsigned long long p = cc
                    ? ((((unsigned long long)__float_as_uint(iou)) << 32) |
                       (unsigned long long)lowkey) : 0ull;
                #pragma unroll
                for (int off = 8; off > 0; off >>= 1) {
                    unsigned long long o = __shfl_xor(p, off);
                    p = o > p ? o : p;
                }
                if (al == 0 && p != 0ull) {
                    atomicMax(cm + n, p);
                    atomicMax((unsigned*)&aq[n].y,   // global warm-up
                        __float_as_uint(
                            __uint_as_float((unsigned)(p >> 32)) * DEFL));
                }
            }
        }

        // ---------------- combine rt across the anchor's 4 chunks ---------
        rt = fmaxf(rt, __shfl_xor(rt, 16));
        rt = fmaxf(rt, __shfl_xor(rt, 32));

        // ---------------- Phase B: replay own records vs final rt ---------
        float bv = 0.0f;   // chunk default (0, bi=0) == numpy all-zero row
        int bi = 0;
        while (rm) {
            int i = __builtin_ctz(rm);
            rm &= rm - 1;
            int n = n0 + i;
            float inter, uni;
            geom(axy, gb[n], area_a, aq[n].x, inter, uni);
            float qa = inter * __builtin_amdgcn_rcpf(uni);
            if (qa >= rt) {                          // final-threshold re-test
                float iou = inter / uni;             // exact IEEE == numpy
                if (iou > bv) { bv = iou; bi = n; }  // strict >: first in chunk
            }
        }

        // ---------------- cross-chunk argmax (first-max tie rule) ---------
        unsigned long long k =
            (((unsigned long long)__float_as_uint(bv)) << 32) |
            (unsigned long long)(unsigned)(NN - bi);
        unsigned long long o;
        o = __shfl_xor(k, 16); k = o > k ? o : k;
        o = __shfl_xor(k, 32); k = o > k ? o : k;

        if (c == 0 && valid) {
            float fbv = __uint_as_float((unsigned)(k >> 32));
            int   fbi = NN - (int)(k & 0xFFFFFFFFull);
            out_slot[(size_t)b * AA + a] = fbi | (fbv > 0.5f ? POS_BIT : 0);
        }
    }
}

// ---------------------------------------------------------------------------
// FUSED encode: scatter folded in via LDS override table (needs colmax in
// ws, outside the boxes region encode overwrites). ovr[rel] = max n whose
// column winner is anchor abase+rel (atomicMax == np last-n-wins). low==0
// prior sentinel rejected by the low>=1 guard.
// ---------------------------------------------------------------------------
__global__ __launch_bounds__(256) void encode_fused_kernel(
        const int* __restrict__ gt_labels,
        const float4* __restrict__ gt_boxes,        // xyxy
        const float4* __restrict__ anchors_cxcywh,
        const unsigned long long* __restrict__ colmax,
        float* __restrict__ out)
{
    const int b = blockIdx.y;
    const int tid = threadIdx.x;
    const int abase = blockIdx.x * 256;

    __shared__ float4 sg[NN];
    __shared__ int    slab[NN];
    __shared__ int    ovr[256];

    ovr[tid] = -1;
    if (tid < NN) {
        sg[tid]   = gt_boxes[b * NN + tid];
        slab[tid] = gt_labels[b * NN + tid];
    }
    __syncthreads();
    if (tid < NN) {
        unsigned long long v = colmax[b * NN + tid];
        unsigned low = (unsigned)(v & 0xFFFFFFFFull);
        if (low >= 1u && low <= (unsigned)AA) {
            int rel = (AA - (int)low) - abase;       // column-winner anchor
            if (rel >= 0 && rel < 256) atomicMax(&ovr[rel], tid);
        }
    }
    __syncthreads();

    const int a = abase + tid;
    if (a >= AA) return;

    const size_t BA = (size_t)BB * AA;
    const size_t base = (size_t)b * AA + a;

    int s = ((const int*)(out + 5 * BA))[base];
    int o = ovr[tid];

    int idx; bool pos;
    if (o >= 0) { idx = o;          pos = true; }
    else        { idx = s & 0x7FFF; pos = (s & POS_BIT) != 0; }

    const float4 g = sg[idx];
    const float gcx = (g.x + g.z) * 0.5f;
    const float gcy = (g.y + g.w) * 0.5f;
    const float gw  = g.z - g.x;
    const float gh  = g.w - g.y;

    const float4 anc = anchors_cxcywh[a];
    const float ecx = (gcx - anc.x) / anc.z;
    const float ecy = (gcy - anc.y) / anc.w;
    const float ew  = logf((gw + EPS_F) / (anc.z + EPS_F));
    const float eh  = logf((gh + EPS_F) / (anc.w + EPS_F));

    out[base] = pos ? (float)slab[idx] : 0.0f;                   // labels
    ((float4*)(out + BA))[base] = make_float4(ecx, ecy, ew, eh); // boxes
    out[5 * BA + base] = pos ? 1.0f : 0.0f;                      // mask
}

// ---------------------------------------------------------------------------
// Fallback scatter + encode (HW-proven): used when ws_size < 51,200 B and
// colmax must alias out's boxes region (consumed before encode overwrites).
// ---------------------------------------------------------------------------
__global__ void scatter_kernel(const unsigned long long* __restrict__ colmax,
                               int* __restrict__ out_slot) {
    const int b = blockIdx.x;
    const int n = threadIdx.x;
    if (n < NN) {
        unsigned long long v = colmax[b * NN + n];
        unsigned low = (unsigned)(v & 0xFFFFFFFFull);
        if (low >= 1u && low <= (unsigned)AA) {
            int idx = AA - (int)low;
            atomicMax(&out_slot[(size_t)b * AA + idx], OVR_FLAG + n);
        }
    }
}

__global__ __launch_bounds__(256) void encode_kernel(
        const int* __restrict__ gt_labels,
        const float4* __restrict__ gt_boxes,        // xyxy
        const float4* __restrict__ anchors_cxcywh,
        float* __restrict__ out)
{
    const int b = blockIdx.y;
    const int tid = threadIdx.x;
    const int a = blockIdx.x * 256 + tid;

    __shared__ float4 sg[NN];
    __shared__ int    slab[NN];
    if (tid < NN) {
        sg[tid]   = gt_boxes[b * NN + tid];
        slab[tid] = gt_labels[b * NN + tid];
    }
    __syncthreads();
    if (a >= AA) return;

    const size_t BA = (size_t)BB * AA;
    const size_t base = (size_t)b * AA + a;

    int s = ((const int*)(out + 5 * BA))[base];

    int idx; bool pos;
    if (s >= OVR_FLAG) { idx = s - OVR_FLAG;  pos = true; }
    else               { idx = s & 0x7FFF;    pos = (s & POS_BIT) != 0; }

    const float4 g = sg[idx];
    const float gcx = (g.x + g.z) * 0.5f;
    const float gcy = (g.y + g.w) * 0.5f;
    const float gw  = g.z - g.x;
    const float gh  = g.w - g.y;

    const float4 anc = anchors_cxcywh[a];
    const float ecx = (gcx - anc.x) / anc.z;
    const float ecy = (gcy - anc.y) / anc.w;
    const float ew  = logf((gw + EPS_F) / (anc.z + EPS_F));
    const float eh  = logf((gh + EPS_F) / (anc.w + EPS_F));

    out[base] = pos ? (float)slab[idx] : 0.0f;                   // labels
    ((float4*)(out + BA))[base] = make_float4(ecx, ecy, ew, eh); // boxes
    out[5 * BA + base] = pos ? 1.0f : 0.0f;                      // mask
}

extern "C" void kernel_launch(void* const* d_in, const int* in_sizes, int n_in,
                              void* d_out, int out_size, void* d_ws, size_t ws_size,
                              hipStream_t stream) {
    const int*    gt_labels    = (const int*)d_in[0];
    const float4* gt_boxes     = (const float4*)d_in[1];
    const float4* anchors_cxcy = (const float4*)d_in[2];
    const float4* anchors_xyxy = (const float4*)d_in[3];
    float* out = (float*)d_out;

    const size_t BA = (size_t)BB * AA;
    int* slot = (int*)(out + 5 * BA);

    // Fused path needs colmax (B*N u64 = 51,200 B) outside out; proven to
    // fit in ws last round. asq {area,scurf} lives in out's boxes region in
    // BOTH paths (only read by iou; encode overwrites it last). Fallback
    // additionally hosts colmax in the boxes region ahead of asq.
    const bool fused = (ws_size >= (size_t)(BB * NN * 8));
    unsigned long long* colmax = fused
        ? (unsigned long long*)d_ws                  // 8B-aligned ws
        : (unsigned long long*)(out + BA);           // boxes region (proven)
    float2* asq = fused
        ? (float2*)(out + BA)                        // boxes region start
        : (float2*)(out + BA + 2 * BB * NN);         // after colmax's u64s

    prior_kernel<<<BB, 128, 0, stream>>>(gt_boxes, anchors_xyxy, colmax, asq);

    iou_row_kernel<<<NSLOT / 4, 256, 0, stream>>>(gt_boxes, anchors_xyxy,
                                                  asq, colmax, slot);

    dim3 egrid(NTILE, BB);    // (35, 64)
    if (fused) {
        encode_fused_kernel<<<egrid, 256, 0, stream>>>(gt_labels, gt_boxes,
                                                       anchors_cxcy, colmax,
                                                       out);
    } else {
        scatter_kernel<<<BB, 128, 0, stream>>>(colmax, slot);
        encode_kernel<<<egrid, 256, 0, stream>>>(gt_labels, gt_boxes,
                                                 anchors_cxcy, out);
    }
}

// Round 4
// 131.442 us; speedup vs baseline: 1.7108x; 1.7108x over previous
//
#include <hip/hip_runtime.h>
#include <math.h>

// CRITICAL: ban FMA contraction file-wide. 1-ulp iou shifts flip near-tie
// argmaxes vs numpy's correctly-rounded ref (rounds 2-4, absmax 69).
#pragma clang fp contract(off)

// Shapes: B=64, N=100, A=8732.
// Out layout (f32 flat): [0,BA) labels | [BA,5BA) boxes | [5BA,6BA) mask
//
// ROUND 4: revert round-3's restructure (divergent VMEM in the inner loop
// stalled: busy-cycles unchanged 113K->125K but span 150K->360K cyc).
// Back to the PROVEN round-2 shape (2240 blocks x 256, lane=anchor, 100-gt
// sequential loop, chunked record masks, in-loop trigger). Single change:
// per-gt operands {g, ag, scurf} are wave-uniform -> read them from a 32B
// per-(b,n) record table via const-restrict uniform addressing so the
// compiler emits s_load (scalar pipe, K$-hot) instead of 2 LDS reads/iter.
// Deletes ds_read_b128+ds_read_b64 (~20cyc/iter), LDS staging and
// __syncthreads. Scurf staleness through K$ is safe: every stored scurf is
// a deflated lower bound of the final column max (same proof as the
// HW-validated LDS warm-up; prior seed is the dominant trigger filter).
//
// colmax u64[B*N]: init by prior (prior_bits<<32 | 0: low=0 loses ties to
// genuine submissions low>=1), atomicMax'd by iou, consumed by encode
// (fused, colmax in ws) or scatter (fallback, colmax in out's boxes region).
// tab f32[B*N*8] {gx,gy,gz,gw, ag, scurf, 0,0}: in out's boxes region after
// the fallback-colmax slot (only read by iou; encode overwrites last).

#define AA 8732
#define NN 100
#define BB 64
#define NTILE 35              // ceil(AA/256)
#define EPS_F 1e-6f
#define OVR_FLAG 0x10000
#define POS_BIT  0x8000
// qa = inter*v_rcp(uni): rel err <= ~1.8e-7. DEFL=1-5e-7 deflation makes all
// filters rigorous one-sided bounds (HW-validated rounds 8/10/11).
#define DEFL 0.9999995f
#define RT_SEED 1e-38f        // > 0: (qa >= rt) implies qa > 0 (validated r3)

__constant__ int FM_SIZE[6] = {38, 19, 10, 5, 3, 1};
__constant__ int FM_NF[6]   = {4, 6, 6, 6, 4, 4};
__constant__ int FM_OFF[6]  = {0, 5776, 7942, 8542, 8692, 8728};

__device__ __forceinline__ void geom(const float4 axy, const float4 g,
                                     float area_a, float ag,
                                     float& inter, float& uni) {
    float ltx = fmaxf(axy.x, g.x);
    float lty = fmaxf(axy.y, g.y);
    float rbx = fminf(axy.z, g.z);
    float rby = fminf(axy.w, g.w);
    float w = fmaxf(rbx - ltx, 0.0f);
    float h = fmaxf(rby - lty, 0.0f);
    inter = w * h;
    uni = area_a + ag - inter;       // uni >= max area > 0 always
}

// ---------------------------------------------------------------------------
// Prior: per (b,n), rcp-approx max IoU over the <=30 center-cell anchors,
// deflated => SAFE lower bound of the column max. Writes colmax init AND the
// 32B record table {g, ag, scurf_seed}.
// ---------------------------------------------------------------------------
__global__ void prior_kernel(const float4* __restrict__ gt_boxes,
                             const float4* __restrict__ anchors_xyxy,
                             unsigned long long* __restrict__ colmax,
                             float4* __restrict__ tab4) {
    const int b = blockIdx.x;
    const int n = threadIdx.x;
    if (n >= NN) return;
    float4 g = gt_boxes[b * NN + n];
    float ag = (g.z - g.x) * (g.w - g.y);
    float cx = (g.x + g.z) * 0.5f;
    float cy = (g.y + g.w) * 0.5f;
    float best = 0.0f;
    for (int f = 0; f < 6; f++) {
        int s = FM_SIZE[f];
        int j = (int)(cx * (float)s); j = j < s - 1 ? j : s - 1;
        int i = (int)(cy * (float)s); i = i < s - 1 ? i : s - 1;
        int base = FM_OFF[f] + (i * s + j) * FM_NF[f];
        for (int k = 0; k < FM_NF[f]; k++) {
            float4 an = anchors_xyxy[base + k];
            float area_a = (an.z - an.x) * (an.w - an.y);
            float inter, uni;
            geom(an, g, area_a, ag, inter, uni);
            best = fmaxf(best, inter * __builtin_amdgcn_rcpf(uni));
        }
    }
    float defl = best * DEFL;        // <= colM*(1-3.2e-7): safe lower bound
    colmax[b * NN + n] = ((unsigned long long)__float_as_uint(defl)) << 32;
    tab4[(b * NN + n) * 2]     = g;
    tab4[(b * NN + n) * 2 + 1] = make_float4(ag, defl, 0.0f, 0.0f);
}

// ---------------------------------------------------------------------------
// Main-pass chunk [N0,N1): identical control flow to the proven round-2
// kernel; operands come from the wave-uniform record table (s_load/K$).
// Row: record mask vs running deflated rt (loop-carried chain is a single
// fmax; qa*DEFL off the critical path); exact div deferred. Col: 1-cmp
// __any trigger vs table scurf (rare after prior priming); on trigger,
// exact div + packed u64 butterfly ((bits<<32)|(AA-a): max iou then lowest
// a), lane 0 submits atomicMax + global scurf warm-up. Clamped clone lanes
// carry anchor AA-1's genuine packed value — idempotent under max.
// ---------------------------------------------------------------------------
template <int N0, int N1>
__device__ __forceinline__ void passChunk(
        const float4 axy, const float area_a, const unsigned lowkey,
        const int tid,
        const float4* __restrict__ tb,              // 2 float4 per gt record
        float* tb_at,                               // same row, atomic target
        unsigned long long* __restrict__ cm,
        float& rt, unsigned& rm)
{
    #pragma unroll 4
    for (int n = N0; n < N1; n++) {
        float4 g = tb[n * 2];
        float4 q = tb[n * 2 + 1];  // .x=ag, .y=scurf (stale = superset, safe)
        float inter, uni;
        geom(axy, g, area_a, q.x, inter, uni);
        float qa = inter * __builtin_amdgcn_rcpf(uni);
        bool r = (qa >= rt);                         // row near-record
        rt = fmaxf(rt, qa * DEFL);
        rm |= (r ? 1u : 0u) << (n - N0);
        if (__any((int)(qa >= q.y))) {               // column trigger (rare)
            float iou = inter / uni;                 // exact IEEE == numpy
            bool cc = (qa >= q.y);
            unsigned long long p = cc
                ? ((((unsigned long long)__float_as_uint(iou)) << 32) |
                   (unsigned long long)lowkey) : 0ull;
            #pragma unroll
            for (int off = 32; off > 0; off >>= 1) {
                unsigned long long o = __shfl_xor(p, off);
                p = o > p ? o : p;
            }
            if ((tid & 63) == 0 && p != 0ull) {
                atomicMax(cm + n, p);
                atomicMax((unsigned*)(tb_at + n * 8 + 5),    // scurf warm-up
                    __float_as_uint(
                        __uint_as_float((unsigned)(p >> 32)) * DEFL));
            }
        }
    }
}

__global__ __launch_bounds__(256, 8) void iou_smem_kernel(
        const float4* __restrict__ anchors_xyxy,    // A
        const float4* __restrict__ tab_ro,          // B*N records (read)
        float* tab_at,                              // same base (atomics)
        unsigned long long* __restrict__ colmax,    // B*N packed, prior-init
        int* __restrict__ out_slot)                 // -> out[5BA..6BA)
{
    const int b = blockIdx.y;
    const int tid = threadIdx.x;
    const int a = blockIdx.x * 256 + tid;
    const bool valid = (a < AA);
    const int ac = valid ? a : (AA - 1);

    const float4* __restrict__ tb = tab_ro + (size_t)b * NN * 2;
    float* tbat = tab_at + (size_t)b * NN * 8;
    unsigned long long* cm = colmax + (size_t)b * NN;

    const float4 axy = anchors_xyxy[ac];
    const float area_a = (axy.z - axy.x) * (axy.w - axy.y);
    const unsigned lowkey = (unsigned)(AA - ac);    // bigger = lower anchor

    // ---------------- Phase A ----------------
    float rt = RT_SEED;            // (qa >= rt) implies qa > 0
    unsigned rm0 = 0, rm1 = 0, rm2 = 0, rm3 = 0;
    passChunk<0, 32>(axy, area_a, lowkey, tid, tb, tbat, cm, rt, rm0);
    passChunk<32, 64>(axy, area_a, lowkey, tid, tb, tbat, cm, rt, rm1);
    passChunk<64, 96>(axy, area_a, lowkey, tid, tb, tbat, cm, rt, rm2);
    passChunk<96, NN>(axy, area_a, lowkey, tid, tb, tbat, cm, rt, rm3);

    // ---------------- Phase B: row replay (ascending n = numpy order) -----
    float bv = 0.0f;   // all-zero row: bv=0, bi=0 == numpy argmax
    int bi = 0;
    unsigned rms[4] = {rm0, rm1, rm2, rm3};
    #pragma unroll
    for (int h = 0; h < 4; h++) {
        unsigned m = rms[h];
        const int nb = h * 32;
        while (m) {
            int n = __builtin_ctz(m) + nb;
            m &= m - 1;
            float inter, uni;
            geom(axy, tb[n * 2], area_a, tb[n * 2 + 1].x, inter, uni);
            float qa = inter * __builtin_amdgcn_rcpf(uni);
            if (qa >= rt) {                          // final-threshold re-test
                float iou = inter / uni;             // exact IEEE == numpy
                if (iou > bv) { bv = iou; bi = n; }  // strict >: first max
            }
        }
    }

    if (valid) {
        // pos decision folded into the slot: exact bv vs 0.5 (override makes
        // pos true anyway; applied later via OVR table / OVR_FLAG).
        out_slot[(size_t)b * AA + a] = bi | (bv > 0.5f ? POS_BIT : 0);
    }
}

// ---------------------------------------------------------------------------
// FUSED encode: scatter folded in via LDS override table (needs colmax in
// ws, outside the boxes region encode overwrites). ovr[rel] = max n whose
// column winner is anchor abase+rel (atomicMax == np last-n-wins). low==0
// prior sentinel rejected by the low>=1 guard.
// ---------------------------------------------------------------------------
__global__ __launch_bounds__(256) void encode_fused_kernel(
        const int* __restrict__ gt_labels,
        const float4* __restrict__ gt_boxes,        // xyxy
        const float4* __restrict__ anchors_cxcywh,
        const unsigned long long* __restrict__ colmax,
        float* __restrict__ out)
{
    const int b = blockIdx.y;
    const int tid = threadIdx.x;
    const int abase = blockIdx.x * 256;

    __shared__ float4 sg[NN];
    __shared__ int    slab[NN];
    __shared__ int    ovr[256];

    ovr[tid] = -1;
    if (tid < NN) {
        sg[tid]   = gt_boxes[b * NN + tid];
        slab[tid] = gt_labels[b * NN + tid];
    }
    __syncthreads();
    if (tid < NN) {
        unsigned long long v = colmax[b * NN + tid];
        unsigned low = (unsigned)(v & 0xFFFFFFFFull);
        if (low >= 1u && low <= (unsigned)AA) {
            int rel = (AA - (int)low) - abase;       // column-winner anchor
            if (rel >= 0 && rel < 256) atomicMax(&ovr[rel], tid);
        }
    }
    __syncthreads();

    const int a = abase + tid;
    if (a >= AA) return;

    const size_t BA = (size_t)BB * AA;
    const size_t base = (size_t)b * AA + a;

    int s = ((const int*)(out + 5 * BA))[base];
    int o = ovr[tid];

    int idx; bool pos;
    if (o >= 0) { idx = o;          pos = true; }
    else        { idx = s & 0x7FFF; pos = (s & POS_BIT) != 0; }

    const float4 g = sg[idx];
    const float gcx = (g.x + g.z) * 0.5f;
    const float gcy = (g.y + g.w) * 0.5f;
    const float gw  = g.z - g.x;
    const float gh  = g.w - g.y;

    const float4 anc = anchors_cxcywh[a];
    const float ecx = (gcx - anc.x) / anc.z;
    const float ecy = (gcy - anc.y) / anc.w;
    const float ew  = logf((gw + EPS_F) / (anc.z + EPS_F));
    const float eh  = logf((gh + EPS_F) / (anc.w + EPS_F));

    out[base] = pos ? (float)slab[idx] : 0.0f;                   // labels
    ((float4*)(out + BA))[base] = make_float4(ecx, ecy, ew, eh); // boxes
    out[5 * BA + base] = pos ? 1.0f : 0.0f;                      // mask
}

// ---------------------------------------------------------------------------
// Fallback scatter + encode (HW-proven): used when ws_size < 51,200 B and
// colmax must alias out's boxes region (consumed before encode overwrites).
// ---------------------------------------------------------------------------
__global__ void scatter_kernel(const unsigned long long* __restrict__ colmax,
                               int* __restrict__ out_slot) {
    const int b = blockIdx.x;
    const int n = threadIdx.x;
    if (n < NN) {
        unsigned long long v = colmax[b * NN + n];
        unsigned low = (unsigned)(v & 0xFFFFFFFFull);
        if (low >= 1u && low <= (unsigned)AA) {
            int idx = AA - (int)low;
            atomicMax(&out_slot[(size_t)b * AA + idx], OVR_FLAG + n);
        }
    }
}

__global__ __launch_bounds__(256) void encode_kernel(
        const int* __restrict__ gt_labels,
        const float4* __restrict__ gt_boxes,        // xyxy
        const float4* __restrict__ anchors_cxcywh,
        float* __restrict__ out)
{
    const int b = blockIdx.y;
    const int tid = threadIdx.x;
    const int a = blockIdx.x * 256 + tid;

    __shared__ float4 sg[NN];
    __shared__ int    slab[NN];
    if (tid < NN) {
        sg[tid]   = gt_boxes[b * NN + tid];
        slab[tid] = gt_labels[b * NN + tid];
    }
    __syncthreads();
    if (a >= AA) return;

    const size_t BA = (size_t)BB * AA;
    const size_t base = (size_t)b * AA + a;

    int s = ((const int*)(out + 5 * BA))[base];

    int idx; bool pos;
    if (s >= OVR_FLAG) { idx = s - OVR_FLAG;  pos = true; }
    else               { idx = s & 0x7FFF;    pos = (s & POS_BIT) != 0; }

    const float4 g = sg[idx];
    const float gcx = (g.x + g.z) * 0.5f;
    const float gcy = (g.y + g.w) * 0.5f;
    const float gw  = g.z - g.x;
    const float gh  = g.w - g.y;

    const float4 anc = anchors_cxcywh[a];
    const float ecx = (gcx - anc.x) / anc.z;
    const float ecy = (gcy - anc.y) / anc.w;
    const float ew  = logf((gw + EPS_F) / (anc.z + EPS_F));
    const float eh  = logf((gh + EPS_F) / (anc.w + EPS_F));

    out[base] = pos ? (float)slab[idx] : 0.0f;                   // labels
    ((float4*)(out + BA))[base] = make_float4(ecx, ecy, ew, eh); // boxes
    out[5 * BA + base] = pos ? 1.0f : 0.0f;                      // mask
}

extern "C" void kernel_launch(void* const* d_in, const int* in_sizes, int n_in,
                              void* d_out, int out_size, void* d_ws, size_t ws_size,
                              hipStream_t stream) {
    const int*    gt_labels    = (const int*)d_in[0];
    const float4* gt_boxes     = (const float4*)d_in[1];
    const float4* anchors_cxcy = (const float4*)d_in[2];
    const float4* anchors_xyxy = (const float4*)d_in[3];
    float* out = (float*)d_out;

    const size_t BA = (size_t)BB * AA;
    int* slot = (int*)(out + 5 * BA);

    // Fused path needs colmax (B*N u64 = 51,200 B) outside out (engaged and
    // proven in round 2: ws >= 51,200). The 32B record table lives in out's
    // boxes region AFTER the fallback-colmax slot (only read by iou; encode
    // overwrites the boxes region last). Offsets identical in both paths.
    const bool fused = (ws_size >= (size_t)(BB * NN * 8));
    unsigned long long* colmax = fused
        ? (unsigned long long*)d_ws                  // 8B-aligned ws
        : (unsigned long long*)(out + BA);           // boxes region (proven)
    float* tabf = out + BA + (size_t)BB * NN * 2;    // skip 51,200 B
    float4* tab4 = (float4*)tabf;

    prior_kernel<<<BB, 128, 0, stream>>>(gt_boxes, anchors_xyxy, colmax, tab4);

    dim3 grid(NTILE, BB);    // (35, 64) — 1 anchor/thread, proven shape
    iou_smem_kernel<<<grid, 256, 0, stream>>>(anchors_xyxy, tab4, tabf,
                                              colmax, slot);
    if (fused) {
        encode_fused_kernel<<<grid, 256, 0, stream>>>(gt_labels, gt_boxes,
                                                      anchors_cxcy, colmax,
                                                      out);
    } else {
        scatter_kernel<<<BB, 128, 0, stream>>>(colmax, slot);
        encode_kernel<<<grid, 256, 0, stream>>>(gt_labels, gt_boxes,
                                                anchors_cxcy, out);
    }
}